// Round 20
// baseline (2329.437 us; speedup 1.0000x reference)
//
#include <hip/hip_runtime.h>
#include <hip/hip_bf16.h>

// MnistModelDP: 2-layer LSTM (H=512) over T=64 frames of 128, B=2048, then proj to 10.
// v18 = v17 (best: 1442us) with ONE change: A-FRAGMENTS DIRECT FROM GLOBAL.
// v17 staged A through LDS (write 16KB + read 32KB per block-iter, 2x duplicated by
// the two col-waves). A-fragments are 16B-contiguous in global (lane l: A[row][k..k+8])
// -> load straight to VGPRs, ping-pong prefetched one iter ahead (issued right after
// the leading barrier => ~600cy cover). LDS read volume halves (the measured binding
// resource: ~770cy/iter of ds_read_b128 vs ~307cy MFMA). B stays LDS-staged (dbuf 32KB),
// counted vmcnt(4/0) — FIFO makes the wait also cover the A-prefetch regs.
// Everything else identical to v17: launch-per-round, layer-balanced CU pairing
// (layer=bid>>8), gate-interleaved B -> in-register cell update, granule-XOR swizzle,
// x=bid&7 XCD weight pinning. fp16 MFMA 16x16x32, fp32 accum.

typedef _Float16 f16x8 __attribute__((ext_vector_type(8)));
typedef float f32x4 __attribute__((ext_vector_type(4)));

#define Bsz 2048
#define Lsz 8192
#define Tsz 64

__global__ void cvt_f32_f16(const float* __restrict__ src, _Float16* __restrict__ dst, int n4) {
    int stride = gridDim.x * blockDim.x;
    for (int i = blockIdx.x * blockDim.x + threadIdx.x; i < n4; i += stride) {
        float4 v = ((const float4*)src)[i];
        union { _Float16 h[4]; ushort4 u; } o;
        o.h[0] = (_Float16)v.x; o.h[1] = (_Float16)v.y;
        o.h[2] = (_Float16)v.z; o.h[3] = (_Float16)v.w;
        ((ushort4*)dst)[i] = o.u;
    }
}

// pack [2048, K1] W_ih (f32) and [2048, 512] W_hh (f32) -> [2048, K1+512] f16
__global__ void pack_w(const float* __restrict__ Wih, const float* __restrict__ Whh,
                       _Float16* __restrict__ dst, int K1) {
    int KT = K1 + 512;
    int n4 = 2048 * KT / 4;
    int stride = gridDim.x * blockDim.x;
    for (int i = blockIdx.x * blockDim.x + threadIdx.x; i < n4; i += stride) {
        int row = i / (KT / 4);
        int col = (i % (KT / 4)) * 4;
        const float* s = (col < K1) ? (Wih + (size_t)row * K1 + col)
                                    : (Whh + (size_t)row * 512 + (col - K1));
        float4 v = *(const float4*)s;
        union { _Float16 h[4]; ushort4 u; } o;
        o.h[0] = (_Float16)v.x; o.h[1] = (_Float16)v.y;
        o.h[2] = (_Float16)v.z; o.h[3] = (_Float16)v.w;
        ((ushort4*)dst)[i] = o.u;
    }
}

__device__ __forceinline__ float fsig(float x)  { return 1.0f / (1.0f + __expf(-x)); }
__device__ __forceinline__ float ftanh(float x) { return 1.0f - 2.0f / (__expf(2.0f * x) + 1.0f); }

__device__ __forceinline__ void gll16(const _Float16* src, char* dst) {
    __builtin_amdgcn_global_load_lds(
        (const __attribute__((address_space(1))) void*)src,
        (__attribute__((address_space(3))) void*)dst, 16, 0, 0);
}

// B tile (128 gate-cols x 64, 16KB), gate-INTERLEAVED: LDS row j -> W row
// gate*512 + cb*32 + hc16*16 + lc. Granule-XOR swizzle via pre-swizzled source col.
template<int K1>
__device__ __forceinline__ void stageB(
    const _Float16* __restrict__ Wcat, int cb, int k0, char* buf, int tid)
{
    constexpr int KT = K1 + 512;
#pragma unroll
    for (int qq = 0; qq < 4; ++qq) {
        const int j  = qq * 32 + (tid >> 3);
        const int cg = (((tid & 7) ^ (j & 7)) << 3);
        const int wrow = ((j >> 4) & 3) * 512 + cb * 32 + (j >> 6) * 16 + (j & 15);
        gll16(Wcat + (size_t)wrow * KT + k0 + cg, buf + qq * 4096 + (tid >> 6) * 1024);
    }
}

// Direct A-fragment load for K-slice it: aX[mi][ks] = A[row(mi)][it*64+ks*32+lhi*8 ..+8]
template<int K1>
__device__ __forceinline__ void loadA(
    f16x8 (*aX)[2],
    const _Float16* const* a1row, const _Float16* const* a2row,
    int it, int lhi)
{
#pragma unroll
    for (int ks = 0; ks < 2; ++ks) {
        const int k = it * 64 + ks * 32 + lhi * 8;
#pragma unroll
        for (int mi = 0; mi < 4; ++mi)
            aX[mi][ks] = (k < K1) ? *(const f16x8*)(a1row[mi] + k)
                                  : *(const f16x8*)(a2row[mi] + (k - K1));
    }
}

// One iteration body: stage B(it+1), counted wait+barrier, prefetch A(it+1) into aL,
// MFMA from aU + LDS B(it), trailing barrier.
template<int K1>
__device__ __forceinline__ void iter_body(
    int it, f16x8 (*aU)[2], f16x8 (*aL)[2],
    const _Float16* const* a1row, const _Float16* const* a2row,
    const _Float16* __restrict__ Wcat, int cb, char* lds, int tid,
    int lhi, int llo, int wc, f32x4 (*acc)[4])
{
    constexpr int KT  = K1 + 512;
    constexpr int NIT = KT / 64;
    if (it + 1 < NIT)
        stageB<K1>(Wcat, cb, (it + 1) * 64, lds + ((it + 1) & 1) * 16384, tid);
    // FIFO: outstanding at wait = [aU(it) 8][B(it) 4][B(it+1) 4] -> vmcnt(4) retires
    // everything but B(it+1): B(it) in LDS ✓, aU regs ready ✓.
    if (it < NIT - 1) asm volatile("s_waitcnt vmcnt(4)" ::: "memory");
    else              asm volatile("s_waitcnt vmcnt(0)" ::: "memory");
    __builtin_amdgcn_s_barrier();
    __builtin_amdgcn_sched_barrier(0);

    if (it + 1 < NIT)
        loadA<K1>(aL, a1row, a2row, it + 1, lhi);   // ~full iter of latency cover

    char* bb = lds + (it & 1) * 16384;
#pragma unroll
    for (int ks = 0; ks < 2; ++ks) {
        const int gsw = (((ks * 4 + lhi) ^ (llo & 7)) << 4);
        f16x8 b[4];
#pragma unroll
        for (int cf = 0; cf < 4; ++cf)
            b[cf] = *(const f16x8*)(bb + (wc * 64 + cf * 16 + llo) * 128 + gsw);
#pragma unroll
        for (int mi = 0; mi < 4; ++mi)
#pragma unroll
            for (int cf = 0; cf < 4; ++cf)
                acc[mi][cf] = __builtin_amdgcn_mfma_f32_16x16x32_f16(
                    aU[mi][ks], b[cf], acc[mi][cf], 0, 0, 0);
    }
    __builtin_amdgcn_s_barrier();        // B readers done before next overwrite
    __builtin_amdgcn_sched_barrier(0);
}

// One LSTM step tile: 128 rows x 128 gate-cols (32 hcols x 4 gates), K=K1+512, BK=64.
// 4 waves as 2x2 of 64x64 wave tiles. A direct-from-global (ping-pong prefetch);
// B LDS dbuf. In-register cell update. MFMA 16x16x32 f16 layouts (passed v2/v4-v17).
template<int K1>
__device__ __forceinline__ void step_v18(
    const _Float16* __restrict__ A1, int lda1,
    const _Float16* __restrict__ A2,
    const _Float16* __restrict__ Wcat,
    const float* __restrict__ bias,
    float* __restrict__ c,
    _Float16* __restrict__ h_out,
    int rowtile, int cb, char* lds)
{
    constexpr int KT  = K1 + 512;
    constexpr int NIT = KT / 64;
    static_assert(NIT % 2 == 0, "even NIT for 2-body unroll");
    const int tid = threadIdx.x;
    const int ln  = tid & 63;
    const int wv  = tid >> 6;
    const int llo = ln & 15, lhi = ln >> 4;
    const int wr  = wv >> 1, wc = wv & 1;

    f32x4 acc[4][4] = {};   // [row-frag mi][gate cf]

    // per-lane A row base pointers
    const _Float16* a1row[4];
    const _Float16* a2row[4];
#pragma unroll
    for (int mi = 0; mi < 4; ++mi) {
        const int row = rowtile * 128 + wr * 64 + mi * 16 + llo;
        a1row[mi] = A1 + (size_t)row * lda1;
        a2row[mi] = A2 + (size_t)row * 512;
    }

    f16x8 aP[4][2], aQ[4][2];

    // prologue: A(0) direct, B(0) staged
    loadA<K1>(aP, a1row, a2row, 0, lhi);
    stageB<K1>(Wcat, cb, 0, lds, tid);

    for (int it2 = 0; it2 < NIT; it2 += 2) {
        iter_body<K1>(it2,     aP, aQ, a1row, a2row, Wcat, cb, lds, tid, lhi, llo, wc, acc);
        iter_body<K1>(it2 + 1, aQ, aP, a1row, a2row, Wcat, cb, lds, tid, lhi, llo, wc, acc);
    }

    // in-register cell update: thread owns 16 row-cells x 1 hcol, all 4 gates in acc.
    const int hcol = cb * 32 + wc * 16 + llo;
    float bz[4];
#pragma unroll
    for (int g = 0; g < 4; ++g) bz[g] = bias[g * 512 + hcol];
#pragma unroll
    for (int mi = 0; mi < 4; ++mi)
#pragma unroll
        for (int rr = 0; rr < 4; ++rr) {
            const int row = rowtile * 128 + wr * 64 + mi * 16 + lhi * 4 + rr;
            const size_t idx = (size_t)row * 512 + hcol;
            float iv = acc[mi][0][rr] + bz[0];
            float fv = acc[mi][1][rr] + bz[1];
            float gv = acc[mi][2][rr] + bz[2];
            float ov = acc[mi][3][rr] + bz[3];
            float cn = fsig(fv) * c[idx] + fsig(iv) * ftanh(gv);
            c[idx] = cn;
            float hn = fsig(ov) * ftanh(cn);
            h_out[idx] = (_Float16)hn;
        }
}

// Paired round: 512 blocks (2/CU). LAYER-BALANCED decode (v17-verified):
//   layer = bid>>8; lb = bid&255: x = lb&7 (XCD), rest = lb>>3: cbh = rest&1,
//   rowtile = rest>>1; cb = x*2+cbh.
__global__ __launch_bounds__(256) void lstm_round(
    int t0, int t1,
    const _Float16* __restrict__ xb16,
    const _Float16* __restrict__ Wc0, const float* __restrict__ b0, float* __restrict__ c0,
    _Float16* __restrict__ h00, _Float16* __restrict__ h01,
    const _Float16* __restrict__ Wc1, const float* __restrict__ b1, float* __restrict__ c1,
    _Float16* __restrict__ h10, _Float16* __restrict__ h11)
{
    __shared__ __align__(16) char lds[32768];
    const int bid     = blockIdx.x;
    const int layer   = bid >> 8;
    const int lb      = bid & 255;
    const int x       = lb & 7;
    const int rest    = lb >> 3;
    const int cb      = x * 2 + (rest & 1);
    const int rowtile = rest >> 1;   // 0..15

    if (layer == 0) {
        if (t0 < 0) return;
        const _Float16* hr = (t0 & 1) ? h01 : h00;
        _Float16*       hw = (t0 & 1) ? h00 : h01;
        step_v18<128>(xb16 + (size_t)t0 * 128, Lsz, hr, Wc0, b0, c0, hw, rowtile, cb, lds);
    } else {
        if (t1 < 0) return;
        const _Float16* h0in = ((t1 + 1) & 1) ? h01 : h00;  // h0 output of step t1
        const _Float16* hr   = (t1 & 1) ? h11 : h10;
        _Float16*       hw   = (t1 & 1) ? h10 : h11;
        step_v18<512>(h0in, 512, hr, Wc1, b1, c1, hw, rowtile, cb, lds);
    }
}

__global__ void proj_kernel(const _Float16* __restrict__ h1,
                            const float* __restrict__ Wout,  // [10, 512]
                            const float* __restrict__ bout,  // [10]
                            float* __restrict__ out)         // [2048, 10]
{
    int tid = blockIdx.x * blockDim.x + threadIdx.x;
    if (tid >= Bsz * 10) return;
    int b = tid / 10, o = tid % 10;
    float s = bout[o];
    const _Float16* hrow = h1 + (size_t)b * 512;
    const float* wrow = Wout + (size_t)o * 512;
    for (int k = 0; k < 512; ++k) s += (float)hrow[k] * wrow[k];
    out[tid] = s;
}

extern "C" void kernel_launch(void* const* d_in, const int* in_sizes, int n_in,
                              void* d_out, int out_size, void* d_ws, size_t ws_size,
                              hipStream_t stream) {
    const float* xb    = (const float*)d_in[0];
    const float* W_ih0 = (const float*)d_in[1];
    const float* W_hh0 = (const float*)d_in[2];
    const float* b0    = (const float*)d_in[3];
    const float* W_ih1 = (const float*)d_in[4];
    const float* W_hh1 = (const float*)d_in[5];
    const float* b1    = (const float*)d_in[6];
    const float* W_out = (const float*)d_in[7];
    const float* b_out = (const float*)d_in[8];
    float* out = (float*)d_out;

    char* ws = (char*)d_ws;
    size_t off = 0;
    auto alloc = [&](size_t bytes) -> void* {
        void* p = ws + off;
        off += (bytes + 255) & ~(size_t)255;
        return p;
    };
    // ~57 MB << 256 MiB ws
    _Float16* xb16 = (_Float16*)alloc((size_t)Bsz * Lsz * 2);
    _Float16* Wc0  = (_Float16*)alloc((size_t)2048 * 640 * 2);
    _Float16* Wc1  = (_Float16*)alloc((size_t)2048 * 1024 * 2);
    _Float16* h00  = (_Float16*)alloc((size_t)Bsz * 512 * 2);
    _Float16* h01  = (_Float16*)alloc((size_t)Bsz * 512 * 2);
    _Float16* h10  = (_Float16*)alloc((size_t)Bsz * 512 * 2);
    _Float16* h11  = (_Float16*)alloc((size_t)Bsz * 512 * 2);
    float* c0 = (float*)alloc((size_t)Bsz * 512 * 4);
    float* c1 = (float*)alloc((size_t)Bsz * 512 * 4);

    cvt_f32_f16<<<2048, 256, 0, stream>>>(xb, xb16, Bsz * Lsz / 4);
    pack_w<<<1280, 256, 0, stream>>>(W_ih0, W_hh0, Wc0, 128);
    pack_w<<<2048, 256, 0, stream>>>(W_ih1, W_hh1, Wc1, 512);

    hipMemsetAsync(h00, 0, (size_t)Bsz * 512 * 2, stream);
    hipMemsetAsync(h10, 0, (size_t)Bsz * 512 * 2, stream);
    hipMemsetAsync(c0, 0, (size_t)Bsz * 512 * 4, stream);
    hipMemsetAsync(c1, 0, (size_t)Bsz * 512 * 4, stream);

    for (int r = 0; r <= Tsz; ++r) {
        int t0 = (r < Tsz) ? r : -1;
        int t1 = r - 1;
        lstm_round<<<dim3(512), 256, 0, stream>>>(t0, t1,
            xb16, Wc0, b0, c0, h00, h01,
            Wc1, b1, c1, h10, h11);
    }

    // final h1 (t=63) written to h10
    proj_kernel<<<(Bsz * 10 + 255) / 256, 256, 0, stream>>>(h10, W_out, b_out, out);
}

// Round 21
// 1446.691 us; speedup vs baseline: 1.6102x; 1.6102x over previous
//
#include <hip/hip_runtime.h>
#include <hip/hip_bf16.h>

// MnistModelDP: 2-layer LSTM (H=512) over T=64 frames of 128, B=2048, then proj to 10.
// v19 = v17 (best: 1442us) + ONE change: s_setprio(1) around the MFMA cluster (T5).
// v17's CUs host one L0 + one L1 block at different phases (layer-balanced pairing) ->
// genuine wave role diversity, T5's verified prerequisite (m218b +21% with role-split,
// m190 0% lockstep). setprio biases the CU scheduler to keep the matrix pipe fed while
// the sibling block stages/barriers.
// [v18 post-mortem: direct-from-global A regressed 1442->2329; per-lane 16B scattered
// loads are request-rate bound (G2) — LDS staging restored.]
// Structure (all verified v15-v17): launch-per-round, tile 128x128, 4 waves, BK=64
// A+B LDS dbuf, counted vmcnt(8/0), gate-interleaved B -> in-register cell update,
// granule-XOR swizzle, x=bid&7 XCD weight pinning, layer=bid>>8 balanced pairing.
// fp16 MFMA 16x16x32, fp32 accum.

typedef _Float16 f16x8 __attribute__((ext_vector_type(8)));
typedef float f32x4 __attribute__((ext_vector_type(4)));

#define Bsz 2048
#define Lsz 8192
#define Tsz 64

__global__ void cvt_f32_f16(const float* __restrict__ src, _Float16* __restrict__ dst, int n4) {
    int stride = gridDim.x * blockDim.x;
    for (int i = blockIdx.x * blockDim.x + threadIdx.x; i < n4; i += stride) {
        float4 v = ((const float4*)src)[i];
        union { _Float16 h[4]; ushort4 u; } o;
        o.h[0] = (_Float16)v.x; o.h[1] = (_Float16)v.y;
        o.h[2] = (_Float16)v.z; o.h[3] = (_Float16)v.w;
        ((ushort4*)dst)[i] = o.u;
    }
}

// pack [2048, K1] W_ih (f32) and [2048, 512] W_hh (f32) -> [2048, K1+512] f16
__global__ void pack_w(const float* __restrict__ Wih, const float* __restrict__ Whh,
                       _Float16* __restrict__ dst, int K1) {
    int KT = K1 + 512;
    int n4 = 2048 * KT / 4;
    int stride = gridDim.x * blockDim.x;
    for (int i = blockIdx.x * blockDim.x + threadIdx.x; i < n4; i += stride) {
        int row = i / (KT / 4);
        int col = (i % (KT / 4)) * 4;
        const float* s = (col < K1) ? (Wih + (size_t)row * K1 + col)
                                    : (Whh + (size_t)row * 512 + (col - K1));
        float4 v = *(const float4*)s;
        union { _Float16 h[4]; ushort4 u; } o;
        o.h[0] = (_Float16)v.x; o.h[1] = (_Float16)v.y;
        o.h[2] = (_Float16)v.z; o.h[3] = (_Float16)v.w;
        ((ushort4*)dst)[i] = o.u;
    }
}

__device__ __forceinline__ float fsig(float x)  { return 1.0f / (1.0f + __expf(-x)); }
__device__ __forceinline__ float ftanh(float x) { return 1.0f - 2.0f / (__expf(2.0f * x) + 1.0f); }

__device__ __forceinline__ void gll16(const _Float16* src, char* dst) {
    __builtin_amdgcn_global_load_lds(
        (const __attribute__((address_space(1))) void*)src,
        (__attribute__((address_space(3))) void*)dst, 16, 0, 0);
}

// B tile (128 gate-cols x 64, 16KB), gate-INTERLEAVED: LDS row j -> W row
// gate*512 + cb*32 + hc16*16 + lc. Granule-XOR swizzle via pre-swizzled source col.
template<int K1>
__device__ __forceinline__ void stageB(
    const _Float16* __restrict__ Wcat, int cb, int k0, char* buf, int tid)
{
    constexpr int KT = K1 + 512;
#pragma unroll
    for (int qq = 0; qq < 4; ++qq) {
        const int j  = qq * 32 + (tid >> 3);
        const int cg = (((tid & 7) ^ (j & 7)) << 3);
        const int wrow = ((j >> 4) & 3) * 512 + cb * 32 + (j >> 6) * 16 + (j & 15);
        gll16(Wcat + (size_t)wrow * KT + k0 + cg, buf + qq * 4096 + (tid >> 6) * 1024);
    }
}

// A tile (128 rows x 64, 16KB). k0 mult of 64, K1%64==0 -> uniform branch.
template<int K1>
__device__ __forceinline__ void stageA(
    const _Float16* __restrict__ A1, int lda1,
    const _Float16* __restrict__ A2,
    int rowtile, int k0, char* buf, int tid)
{
#pragma unroll
    for (int qq = 0; qq < 4; ++qq) {
        const int row  = qq * 32 + (tid >> 3);
        const int cg   = (((tid & 7) ^ (row & 7)) << 3);
        const int brow = rowtile * 128 + row;
        char* d = buf + qq * 4096 + (tid >> 6) * 1024;
        if (k0 < K1) gll16(A1 + (size_t)brow * lda1 + k0 + cg, d);
        else         gll16(A2 + (size_t)brow * 512 + (k0 - K1) + cg, d);
    }
}

// One LSTM step tile: 128 rows x 128 gate-cols (32 hcols x 4 gates), K=K1+512, BK=64.
// 4 waves as 2x2 of 64x64 wave tiles. Wave holds all 4 gates for hcols cb*32+wc*16+llo
// -> in-register cell update (c via global fp32).
// Counted-vmcnt: prologue [A0,B0]; per it issue [B(it+1),A(it+1)]; vmcnt(8)/0.
// MFMA cluster wrapped in s_setprio(1)/(0) (T5). Layouts passed v2/v4-v17.
template<int K1>
__device__ __forceinline__ void step_v19(
    const _Float16* __restrict__ A1, int lda1,
    const _Float16* __restrict__ A2,
    const _Float16* __restrict__ Wcat,
    const float* __restrict__ bias,
    float* __restrict__ c,
    _Float16* __restrict__ h_out,
    int rowtile, int cb, char* lds)
{
    constexpr int KT  = K1 + 512;
    constexpr int NIT = KT / 64;
    const int tid = threadIdx.x;
    const int ln  = tid & 63;
    const int wv  = tid >> 6;
    const int llo = ln & 15, lhi = ln >> 4;
    const int wr  = wv >> 1, wc = wv & 1;

    f32x4 acc[4][4] = {};   // [row-frag mi][gate cf]

    // prologue: A0, B0
    stageA<K1>(A1, lda1, A2, rowtile, 0, lds + 32768, tid);
    stageB<K1>(Wcat, cb, 0, lds, tid);

    for (int it = 0; it < NIT; ++it) {
        if (it + 1 < NIT) {
            stageB<K1>(Wcat, cb, (it + 1) * 64, lds + ((it + 1) & 1) * 16384, tid);
            stageA<K1>(A1, lda1, A2, rowtile, (it + 1) * 64,
                       lds + 32768 + ((it + 1) & 1) * 16384, tid);
        }
        // outstanding after tile-it's loads: B(it+1) 4 + A(it+1) 4 = 8; 0 at NIT-1
        if (it < NIT - 1) asm volatile("s_waitcnt vmcnt(8)" ::: "memory");
        else              asm volatile("s_waitcnt vmcnt(0)" ::: "memory");
        __builtin_amdgcn_s_barrier();
        __builtin_amdgcn_sched_barrier(0);

        char* bb = lds + (it & 1) * 16384;
        char* ab = lds + 32768 + (it & 1) * 16384;
        __builtin_amdgcn_s_setprio(1);
#pragma unroll
        for (int ks = 0; ks < 2; ++ks) {
            const int gsw = (((ks * 4 + lhi) ^ (llo & 7)) << 4);
            f16x8 a[4], b[4];
#pragma unroll
            for (int mi = 0; mi < 4; ++mi)
                a[mi] = *(const f16x8*)(ab + (wr * 64 + mi * 16 + llo) * 128 + gsw);
#pragma unroll
            for (int cf = 0; cf < 4; ++cf)
                b[cf] = *(const f16x8*)(bb + (wc * 64 + cf * 16 + llo) * 128 + gsw);
#pragma unroll
            for (int mi = 0; mi < 4; ++mi)
#pragma unroll
                for (int cf = 0; cf < 4; ++cf)
                    acc[mi][cf] = __builtin_amdgcn_mfma_f32_16x16x32_f16(
                        a[mi], b[cf], acc[mi][cf], 0, 0, 0);
        }
        __builtin_amdgcn_s_setprio(0);
        __builtin_amdgcn_s_barrier();        // readers done before next overwrite
        __builtin_amdgcn_sched_barrier(0);
    }

    // in-register cell update: thread owns 16 row-cells x 1 hcol, all 4 gates in acc.
    const int hcol = cb * 32 + wc * 16 + llo;
    float bz[4];
#pragma unroll
    for (int g = 0; g < 4; ++g) bz[g] = bias[g * 512 + hcol];
#pragma unroll
    for (int mi = 0; mi < 4; ++mi)
#pragma unroll
        for (int rr = 0; rr < 4; ++rr) {
            const int row = rowtile * 128 + wr * 64 + mi * 16 + lhi * 4 + rr;
            const size_t idx = (size_t)row * 512 + hcol;
            float iv = acc[mi][0][rr] + bz[0];
            float fv = acc[mi][1][rr] + bz[1];
            float gv = acc[mi][2][rr] + bz[2];
            float ov = acc[mi][3][rr] + bz[3];
            float cn = fsig(fv) * c[idx] + fsig(iv) * ftanh(gv);
            c[idx] = cn;
            float hn = fsig(ov) * ftanh(cn);
            h_out[idx] = (_Float16)hn;
        }
}

// Paired round: 512 blocks (2/CU via 64KB LDS). LAYER-BALANCED decode (v17-verified):
//   layer = bid>>8; lb = bid&255: x = lb&7 (XCD), rest = lb>>3: cbh = rest&1,
//   rowtile = rest>>1; cb = x*2+cbh.
__global__ __launch_bounds__(256) void lstm_round(
    int t0, int t1,
    const _Float16* __restrict__ xb16,
    const _Float16* __restrict__ Wc0, const float* __restrict__ b0, float* __restrict__ c0,
    _Float16* __restrict__ h00, _Float16* __restrict__ h01,
    const _Float16* __restrict__ Wc1, const float* __restrict__ b1, float* __restrict__ c1,
    _Float16* __restrict__ h10, _Float16* __restrict__ h11)
{
    __shared__ __align__(16) char lds[65536];
    const int bid     = blockIdx.x;
    const int layer   = bid >> 8;
    const int lb      = bid & 255;
    const int x       = lb & 7;
    const int rest    = lb >> 3;
    const int cb      = x * 2 + (rest & 1);
    const int rowtile = rest >> 1;   // 0..15

    if (layer == 0) {
        if (t0 < 0) return;
        const _Float16* hr = (t0 & 1) ? h01 : h00;
        _Float16*       hw = (t0 & 1) ? h00 : h01;
        step_v19<128>(xb16 + (size_t)t0 * 128, Lsz, hr, Wc0, b0, c0, hw, rowtile, cb, lds);
    } else {
        if (t1 < 0) return;
        const _Float16* h0in = ((t1 + 1) & 1) ? h01 : h00;  // h0 output of step t1
        const _Float16* hr   = (t1 & 1) ? h11 : h10;
        _Float16*       hw   = (t1 & 1) ? h10 : h11;
        step_v19<512>(h0in, 512, hr, Wc1, b1, c1, hw, rowtile, cb, lds);
    }
}

__global__ void proj_kernel(const _Float16* __restrict__ h1,
                            const float* __restrict__ Wout,  // [10, 512]
                            const float* __restrict__ bout,  // [10]
                            float* __restrict__ out)         // [2048, 10]
{
    int tid = blockIdx.x * blockDim.x + threadIdx.x;
    if (tid >= Bsz * 10) return;
    int b = tid / 10, o = tid % 10;
    float s = bout[o];
    const _Float16* hrow = h1 + (size_t)b * 512;
    const float* wrow = Wout + (size_t)o * 512;
    for (int k = 0; k < 512; ++k) s += (float)hrow[k] * wrow[k];
    out[tid] = s;
}

extern "C" void kernel_launch(void* const* d_in, const int* in_sizes, int n_in,
                              void* d_out, int out_size, void* d_ws, size_t ws_size,
                              hipStream_t stream) {
    const float* xb    = (const float*)d_in[0];
    const float* W_ih0 = (const float*)d_in[1];
    const float* W_hh0 = (const float*)d_in[2];
    const float* b0    = (const float*)d_in[3];
    const float* W_ih1 = (const float*)d_in[4];
    const float* W_hh1 = (const float*)d_in[5];
    const float* b1    = (const float*)d_in[6];
    const float* W_out = (const float*)d_in[7];
    const float* b_out = (const float*)d_in[8];
    float* out = (float*)d_out;

    char* ws = (char*)d_ws;
    size_t off = 0;
    auto alloc = [&](size_t bytes) -> void* {
        void* p = ws + off;
        off += (bytes + 255) & ~(size_t)255;
        return p;
    };
    // ~57 MB << 256 MiB ws
    _Float16* xb16 = (_Float16*)alloc((size_t)Bsz * Lsz * 2);
    _Float16* Wc0  = (_Float16*)alloc((size_t)2048 * 640 * 2);
    _Float16* Wc1  = (_Float16*)alloc((size_t)2048 * 1024 * 2);
    _Float16* h00  = (_Float16*)alloc((size_t)Bsz * 512 * 2);
    _Float16* h01  = (_Float16*)alloc((size_t)Bsz * 512 * 2);
    _Float16* h10  = (_Float16*)alloc((size_t)Bsz * 512 * 2);
    _Float16* h11  = (_Float16*)alloc((size_t)Bsz * 512 * 2);
    float* c0 = (float*)alloc((size_t)Bsz * 512 * 4);
    float* c1 = (float*)alloc((size_t)Bsz * 512 * 4);

    cvt_f32_f16<<<2048, 256, 0, stream>>>(xb, xb16, Bsz * Lsz / 4);
    pack_w<<<1280, 256, 0, stream>>>(W_ih0, W_hh0, Wc0, 128);
    pack_w<<<2048, 256, 0, stream>>>(W_ih1, W_hh1, Wc1, 512);

    hipMemsetAsync(h00, 0, (size_t)Bsz * 512 * 2, stream);
    hipMemsetAsync(h10, 0, (size_t)Bsz * 512 * 2, stream);
    hipMemsetAsync(c0, 0, (size_t)Bsz * 512 * 4, stream);
    hipMemsetAsync(c1, 0, (size_t)Bsz * 512 * 4, stream);

    for (int r = 0; r <= Tsz; ++r) {
        int t0 = (r < Tsz) ? r : -1;
        int t1 = r - 1;
        lstm_round<<<dim3(512), 256, 0, stream>>>(t0, t1,
            xb16, Wc0, b0, c0, h00, h01,
            Wc1, b1, c1, h10, h11);
    }

    // final h1 (t=63) written to h10
    proj_kernel<<<(Bsz * 10 + 255) / 256, 256, 0, stream>>>(h10, W_out, b_out, out);
}

// Round 22
// 1431.821 us; speedup vs baseline: 1.6269x; 1.0104x over previous
//
#include <hip/hip_runtime.h>
#include <hip/hip_bf16.h>

// MnistModelDP: 2-layer LSTM (H=512) over T=64 frames of 128, B=2048, then proj to 10.
// v20 = v17 (best: 1442us) + ONE structural change: SINGLE BARRIER PER K-ITER.
// Stage-issues moved AFTER the leading barrier: the trailing barrier's hazard (stage
// data returning into a buffer slower waves still read) vanishes because issue now
// happens only after ALL waves passed barrier(it) (i.e., finished compute(it-1), the
// last readers of the overwritten slots). Rings: B depth 2 (32KB), A depth 3 (48KB)
// = 80KB -> still 2 blocks/CU. FIFO vmcnt ledger (4-load units, prologue A0,B0,A1):
// entering iter it: [A(it) 4][B(it) 4][A(it+1) 4] -> vmcnt(4); tail NIT-1 -> vmcnt(0).
// Fast-wave race: writes B[(it+1)&1], A[(it+2)%3] are disjoint from compute(it)'s
// B[it&1], A[it%3] (it,it+1,it+2 distinct mod 3). Hand-verified.
// Everything else v17-verbatim: launch-per-round, layer-balanced pairing (layer=bid>>8),
// gate-interleaved B -> in-register cell update, granule-XOR swizzle, x=bid&7 XCD
// weight pinning. fp16 MFMA 16x16x32, fp32 accum. [v18 direct-A regressed: G2; v19
// setprio null: stall is sync-intrinsic, not arbitration.]

typedef _Float16 f16x8 __attribute__((ext_vector_type(8)));
typedef float f32x4 __attribute__((ext_vector_type(4)));

#define Bsz 2048
#define Lsz 8192
#define Tsz 64

__global__ void cvt_f32_f16(const float* __restrict__ src, _Float16* __restrict__ dst, int n4) {
    int stride = gridDim.x * blockDim.x;
    for (int i = blockIdx.x * blockDim.x + threadIdx.x; i < n4; i += stride) {
        float4 v = ((const float4*)src)[i];
        union { _Float16 h[4]; ushort4 u; } o;
        o.h[0] = (_Float16)v.x; o.h[1] = (_Float16)v.y;
        o.h[2] = (_Float16)v.z; o.h[3] = (_Float16)v.w;
        ((ushort4*)dst)[i] = o.u;
    }
}

// pack [2048, K1] W_ih (f32) and [2048, 512] W_hh (f32) -> [2048, K1+512] f16
__global__ void pack_w(const float* __restrict__ Wih, const float* __restrict__ Whh,
                       _Float16* __restrict__ dst, int K1) {
    int KT = K1 + 512;
    int n4 = 2048 * KT / 4;
    int stride = gridDim.x * blockDim.x;
    for (int i = blockIdx.x * blockDim.x + threadIdx.x; i < n4; i += stride) {
        int row = i / (KT / 4);
        int col = (i % (KT / 4)) * 4;
        const float* s = (col < K1) ? (Wih + (size_t)row * K1 + col)
                                    : (Whh + (size_t)row * 512 + (col - K1));
        float4 v = *(const float4*)s;
        union { _Float16 h[4]; ushort4 u; } o;
        o.h[0] = (_Float16)v.x; o.h[1] = (_Float16)v.y;
        o.h[2] = (_Float16)v.z; o.h[3] = (_Float16)v.w;
        ((ushort4*)dst)[i] = o.u;
    }
}

__device__ __forceinline__ float fsig(float x)  { return 1.0f / (1.0f + __expf(-x)); }
__device__ __forceinline__ float ftanh(float x) { return 1.0f - 2.0f / (__expf(2.0f * x) + 1.0f); }

__device__ __forceinline__ void gll16(const _Float16* src, char* dst) {
    __builtin_amdgcn_global_load_lds(
        (const __attribute__((address_space(1))) void*)src,
        (__attribute__((address_space(3))) void*)dst, 16, 0, 0);
}

// B tile (128 gate-cols x 64, 16KB), gate-INTERLEAVED: LDS row j -> W row
// gate*512 + cb*32 + hc16*16 + lc. Granule-XOR swizzle via pre-swizzled source col.
template<int K1>
__device__ __forceinline__ void stageB(
    const _Float16* __restrict__ Wcat, int cb, int k0, char* buf, int tid)
{
    constexpr int KT = K1 + 512;
#pragma unroll
    for (int qq = 0; qq < 4; ++qq) {
        const int j  = qq * 32 + (tid >> 3);
        const int cg = (((tid & 7) ^ (j & 7)) << 3);
        const int wrow = ((j >> 4) & 3) * 512 + cb * 32 + (j >> 6) * 16 + (j & 15);
        gll16(Wcat + (size_t)wrow * KT + k0 + cg, buf + qq * 4096 + (tid >> 6) * 1024);
    }
}

// A tile (128 rows x 64, 16KB). k0 mult of 64, K1%64==0 -> uniform branch.
template<int K1>
__device__ __forceinline__ void stageA(
    const _Float16* __restrict__ A1, int lda1,
    const _Float16* __restrict__ A2,
    int rowtile, int k0, char* buf, int tid)
{
#pragma unroll
    for (int qq = 0; qq < 4; ++qq) {
        const int row  = qq * 32 + (tid >> 3);
        const int cg   = (((tid & 7) ^ (row & 7)) << 3);
        const int brow = rowtile * 128 + row;
        char* d = buf + qq * 4096 + (tid >> 6) * 1024;
        if (k0 < K1) gll16(A1 + (size_t)brow * lda1 + k0 + cg, d);
        else         gll16(A2 + (size_t)brow * 512 + (k0 - K1) + cg, d);
    }
}

// One LSTM step tile: 128 rows x 128 gate-cols (32 hcols x 4 gates), K=K1+512, BK=64.
// 4 waves as 2x2 of 64x64 wave tiles. Wave holds all 4 gates for hcols cb*32+wc*16+llo
// -> in-register cell update (c via global fp32).
// Single-barrier pipeline: prologue [A0,B0,A1]; per it: vmcnt(4|0) -> s_barrier ->
// issue [B(it+1), A(it+2)] -> compute(it). B ring2 @0, A ring3 @32768.
// MFMA 16x16x32 f16 layouts (passed v2/v4-v19).
template<int K1>
__device__ __forceinline__ void step_v20(
    const _Float16* __restrict__ A1, int lda1,
    const _Float16* __restrict__ A2,
    const _Float16* __restrict__ Wcat,
    const float* __restrict__ bias,
    float* __restrict__ c,
    _Float16* __restrict__ h_out,
    int rowtile, int cb, char* lds)
{
    constexpr int KT  = K1 + 512;
    constexpr int NIT = KT / 64;
    const int tid = threadIdx.x;
    const int ln  = tid & 63;
    const int wv  = tid >> 6;
    const int llo = ln & 15, lhi = ln >> 4;
    const int wr  = wv >> 1, wc = wv & 1;

    f32x4 acc[4][4] = {};   // [row-frag mi][gate cf]

    // prologue: A0 -> Aring[0], B0 -> Bring[0], A1 -> Aring[1]  (FIFO: A0,B0,A1)
    stageA<K1>(A1, lda1, A2, rowtile, 0, lds + 32768, tid);
    stageB<K1>(Wcat, cb, 0, lds, tid);
    stageA<K1>(A1, lda1, A2, rowtile, 64, lds + 32768 + 16384, tid);

    int am0 = 0;   // it % 3 (avoid div)
    for (int it = 0; it < NIT; ++it) {
        // FIFO at entry: [A(it) 4][B(it) 4][A(it+1) 4] -> vmcnt(4) retires A(it),B(it)
        if (it < NIT - 1) asm volatile("s_waitcnt vmcnt(4)" ::: "memory");
        else              asm volatile("s_waitcnt vmcnt(0)" ::: "memory");
        __builtin_amdgcn_s_barrier();
        __builtin_amdgcn_sched_barrier(0);

        // issue next tiles AFTER barrier: overwritten slots' last readers (compute(it-1))
        // are provably done. B(it+1) -> Bring[(it+1)&1]; A(it+2) -> Aring[(it+2)%3].
        if (it + 1 < NIT)
            stageB<K1>(Wcat, cb, (it + 1) * 64, lds + ((it + 1) & 1) * 16384, tid);
        if (it + 2 < NIT) {
            int am2 = am0 + 2; if (am2 >= 3) am2 -= 3;
            stageA<K1>(A1, lda1, A2, rowtile, (it + 2) * 64,
                       lds + 32768 + am2 * 16384, tid);
        }
        __builtin_amdgcn_sched_barrier(0);

        char* bb = lds + (it & 1) * 16384;
        char* ab = lds + 32768 + am0 * 16384;
#pragma unroll
        for (int ks = 0; ks < 2; ++ks) {
            const int gsw = (((ks * 4 + lhi) ^ (llo & 7)) << 4);
            f16x8 a[4], b[4];
#pragma unroll
            for (int mi = 0; mi < 4; ++mi)
                a[mi] = *(const f16x8*)(ab + (wr * 64 + mi * 16 + llo) * 128 + gsw);
#pragma unroll
            for (int cf = 0; cf < 4; ++cf)
                b[cf] = *(const f16x8*)(bb + (wc * 64 + cf * 16 + llo) * 128 + gsw);
#pragma unroll
            for (int mi = 0; mi < 4; ++mi)
#pragma unroll
                for (int cf = 0; cf < 4; ++cf)
                    acc[mi][cf] = __builtin_amdgcn_mfma_f32_16x16x32_f16(
                        a[mi], b[cf], acc[mi][cf], 0, 0, 0);
        }
        ++am0; if (am0 >= 3) am0 -= 3;
    }

    // in-register cell update: thread owns 16 row-cells x 1 hcol, all 4 gates in acc.
    const int hcol = cb * 32 + wc * 16 + llo;
    float bz[4];
#pragma unroll
    for (int g = 0; g < 4; ++g) bz[g] = bias[g * 512 + hcol];
#pragma unroll
    for (int mi = 0; mi < 4; ++mi)
#pragma unroll
        for (int rr = 0; rr < 4; ++rr) {
            const int row = rowtile * 128 + wr * 64 + mi * 16 + lhi * 4 + rr;
            const size_t idx = (size_t)row * 512 + hcol;
            float iv = acc[mi][0][rr] + bz[0];
            float fv = acc[mi][1][rr] + bz[1];
            float gv = acc[mi][2][rr] + bz[2];
            float ov = acc[mi][3][rr] + bz[3];
            float cn = fsig(fv) * c[idx] + fsig(iv) * ftanh(gv);
            c[idx] = cn;
            float hn = fsig(ov) * ftanh(cn);
            h_out[idx] = (_Float16)hn;
        }
}

// Paired round: 512 blocks (2/CU via 80KB LDS). LAYER-BALANCED decode (v17-verified):
//   layer = bid>>8; lb = bid&255: x = lb&7 (XCD), rest = lb>>3: cbh = rest&1,
//   rowtile = rest>>1; cb = x*2+cbh.
__global__ __launch_bounds__(256) void lstm_round(
    int t0, int t1,
    const _Float16* __restrict__ xb16,
    const _Float16* __restrict__ Wc0, const float* __restrict__ b0, float* __restrict__ c0,
    _Float16* __restrict__ h00, _Float16* __restrict__ h01,
    const _Float16* __restrict__ Wc1, const float* __restrict__ b1, float* __restrict__ c1,
    _Float16* __restrict__ h10, _Float16* __restrict__ h11)
{
    __shared__ __align__(16) char lds[81920];
    const int bid     = blockIdx.x;
    const int layer   = bid >> 8;
    const int lb      = bid & 255;
    const int x       = lb & 7;
    const int rest    = lb >> 3;
    const int cb      = x * 2 + (rest & 1);
    const int rowtile = rest >> 1;   // 0..15

    if (layer == 0) {
        if (t0 < 0) return;
        const _Float16* hr = (t0 & 1) ? h01 : h00;
        _Float16*       hw = (t0 & 1) ? h00 : h01;
        step_v20<128>(xb16 + (size_t)t0 * 128, Lsz, hr, Wc0, b0, c0, hw, rowtile, cb, lds);
    } else {
        if (t1 < 0) return;
        const _Float16* h0in = ((t1 + 1) & 1) ? h01 : h00;  // h0 output of step t1
        const _Float16* hr   = (t1 & 1) ? h11 : h10;
        _Float16*       hw   = (t1 & 1) ? h10 : h11;
        step_v20<512>(h0in, 512, hr, Wc1, b1, c1, hw, rowtile, cb, lds);
    }
}

__global__ void proj_kernel(const _Float16* __restrict__ h1,
                            const float* __restrict__ Wout,  // [10, 512]
                            const float* __restrict__ bout,  // [10]
                            float* __restrict__ out)         // [2048, 10]
{
    int tid = blockIdx.x * blockDim.x + threadIdx.x;
    if (tid >= Bsz * 10) return;
    int b = tid / 10, o = tid % 10;
    float s = bout[o];
    const _Float16* hrow = h1 + (size_t)b * 512;
    const float* wrow = Wout + (size_t)o * 512;
    for (int k = 0; k < 512; ++k) s += (float)hrow[k] * wrow[k];
    out[tid] = s;
}

extern "C" void kernel_launch(void* const* d_in, const int* in_sizes, int n_in,
                              void* d_out, int out_size, void* d_ws, size_t ws_size,
                              hipStream_t stream) {
    const float* xb    = (const float*)d_in[0];
    const float* W_ih0 = (const float*)d_in[1];
    const float* W_hh0 = (const float*)d_in[2];
    const float* b0    = (const float*)d_in[3];
    const float* W_ih1 = (const float*)d_in[4];
    const float* W_hh1 = (const float*)d_in[5];
    const float* b1    = (const float*)d_in[6];
    const float* W_out = (const float*)d_in[7];
    const float* b_out = (const float*)d_in[8];
    float* out = (float*)d_out;

    char* ws = (char*)d_ws;
    size_t off = 0;
    auto alloc = [&](size_t bytes) -> void* {
        void* p = ws + off;
        off += (bytes + 255) & ~(size_t)255;
        return p;
    };
    // ~57 MB << 256 MiB ws
    _Float16* xb16 = (_Float16*)alloc((size_t)Bsz * Lsz * 2);
    _Float16* Wc0  = (_Float16*)alloc((size_t)2048 * 640 * 2);
    _Float16* Wc1  = (_Float16*)alloc((size_t)2048 * 1024 * 2);
    _Float16* h00  = (_Float16*)alloc((size_t)Bsz * 512 * 2);
    _Float16* h01  = (_Float16*)alloc((size_t)Bsz * 512 * 2);
    _Float16* h10  = (_Float16*)alloc((size_t)Bsz * 512 * 2);
    _Float16* h11  = (_Float16*)alloc((size_t)Bsz * 512 * 2);
    float* c0 = (float*)alloc((size_t)Bsz * 512 * 4);
    float* c1 = (float*)alloc((size_t)Bsz * 512 * 4);

    cvt_f32_f16<<<2048, 256, 0, stream>>>(xb, xb16, Bsz * Lsz / 4);
    pack_w<<<1280, 256, 0, stream>>>(W_ih0, W_hh0, Wc0, 128);
    pack_w<<<2048, 256, 0, stream>>>(W_ih1, W_hh1, Wc1, 512);

    hipMemsetAsync(h00, 0, (size_t)Bsz * 512 * 2, stream);
    hipMemsetAsync(h10, 0, (size_t)Bsz * 512 * 2, stream);
    hipMemsetAsync(c0, 0, (size_t)Bsz * 512 * 4, stream);
    hipMemsetAsync(c1, 0, (size_t)Bsz * 512 * 4, stream);

    for (int r = 0; r <= Tsz; ++r) {
        int t0 = (r < Tsz) ? r : -1;
        int t1 = r - 1;
        lstm_round<<<dim3(512), 256, 0, stream>>>(t0, t1,
            xb16, Wc0, b0, c0, h00, h01,
            Wc1, b1, c1, h10, h11);
    }

    // final h1 (t=63) written to h10
    proj_kernel<<<(Bsz * 10 + 255) / 256, 256, 0, stream>>>(h10, W_out, b_out, out);
}